// Round 1
// baseline (1601.608 us; speedup 1.0000x reference)
//
#include <hip/hip_runtime.h>
#include <float.h>

#define P 2048
#define N 131072
#define D 128
#define G 32               // prototypes per block
#define NS 8               // slices of N (grid = (P/G)*NS = 512 blocks)
#define NPB (N / NS)       // points per block slice = 16384
#define BT 256             // threads per block
#define PPL 2              // points per lane per chunk
#define CP (BT * PPL)      // points per chunk = 512
#define NCHUNK (NPB / CP)  // 32
#define CAND_CAP 16

// ---------------------------------------------------------------------------
// Kernel 1: fused dot-products + online top-8 per prototype (per N-slice).
// Writes partial top-8 (dot, idx) per (prototype, slice) to workspace.
// ---------------------------------------------------------------------------
__global__ __launch_bounds__(BT) void topk_kernel(
    const float* __restrict__ protos, const float* __restrict__ mem,
    float* __restrict__ part_dot, int* __restrict__ part_idx)
{
  __shared__ __align__(16) float sP[G][D];   // 16 KB prototype tile
  __shared__ float thresh[G];
  __shared__ int   cand_cnt[G];
  __shared__ float cand_dot[G][CAND_CAP];
  __shared__ int   cand_idx[G][CAND_CAP];
  __shared__ float wv_dot[G][4][8];          // per-wave top-8 staging (overflow path)
  __shared__ int   wv_idx[G][4][8];
  __shared__ float top_dot[G][8];
  __shared__ int   top_idx[G][8];

  const int tid  = threadIdx.x;
  const int lane = tid & 63;
  const int wid  = tid >> 6;
  const int pg   = blockIdx.x >> 3;          // prototype group 0..63
  const int ns   = blockIdx.x & (NS - 1);    // slice 0..7

  // stage G prototype rows into LDS (coalesced float4)
  {
    const float4* src = (const float4*)(protos + (size_t)pg * G * D);
    float4* dst = (float4*)&sP[0][0];
    for (int i = tid; i < G * D / 4; i += BT) dst[i] = src[i];
  }
  if (tid < G) { thresh[tid] = -FLT_MAX; cand_cnt[tid] = 0; }
  top_dot[tid >> 3][tid & 7] = -FLT_MAX;
  top_idx[tid >> 3][tid & 7] = 0;
  __syncthreads();

  for (int c = 0; c < NCHUNK; ++c) {
    const int p0 = ns * NPB + c * CP + tid;
    const int p1 = p0 + BT;
    const float4* r0 = (const float4*)(mem + (size_t)p0 * D);
    const float4* r1 = (const float4*)(mem + (size_t)p1 * D);

    float acc0[G], acc1[G];
    #pragma unroll
    for (int g = 0; g < G; ++g) { acc0[g] = 0.f; acc1[g] = 0.f; }

    #pragma unroll 1
    for (int dq = 0; dq < D / 4; ++dq) {
      float4 a = r0[dq];
      float4 b = r1[dq];
      #pragma unroll
      for (int g = 0; g < G; ++g) {
        float4 pr = *(const float4*)&sP[g][dq * 4];   // wave-uniform broadcast
        acc0[g] = fmaf(a.w, pr.w, fmaf(a.z, pr.z, fmaf(a.y, pr.y, fmaf(a.x, pr.x, acc0[g]))));
        acc1[g] = fmaf(b.w, pr.w, fmaf(b.z, pr.z, fmaf(b.y, pr.y, fmaf(b.x, pr.x, acc1[g]))));
      }
    }

    // fast path: threshold test + rare candidate append
    #pragma unroll
    for (int g = 0; g < G; ++g) {
      const float t = thresh[g];
      if (acc0[g] > t) {
        int s = atomicAdd(&cand_cnt[g], 1);
        if (s < CAND_CAP) { cand_dot[g][s] = acc0[g]; cand_idx[g][s] = p0; }
      }
      if (acc1[g] > t) {
        int s = atomicAdd(&cand_cnt[g], 1);
        if (s < CAND_CAP) { cand_dot[g][s] = acc1[g]; cand_idx[g][s] = p1; }
      }
    }
    __syncthreads();

    // overflow path: exact per-wave top-8 (argmax-extract, 8 iterations)
    #pragma unroll 1
    for (int g = 0; g < G; ++g) {
      if (cand_cnt[g] > CAND_CAP) {
        float v0 = acc0[g]; int i0 = p0;
        float v1 = acc1[g]; int i1 = p1;
        #pragma unroll 1
        for (int k = 0; k < 8; ++k) {
          float m; int mi;
          if (v0 >= v1) { m = v0; mi = i0; } else { m = v1; mi = i1; }
          #pragma unroll
          for (int off = 32; off > 0; off >>= 1) {
            float om  = __shfl_xor(m, off);
            int   omi = __shfl_xor(mi, off);
            if (om > m || (om == m && omi < mi)) { m = om; mi = omi; }
          }
          if (lane == 0) { wv_dot[g][wid][k] = m; wv_idx[g][wid][k] = mi; }
          if (i0 == mi) v0 = -FLT_MAX;   // remove selected value (unique index)
          if (i1 == mi) v1 = -FLT_MAX;
        }
      }
    }
    __syncthreads();

    // owner phase: thread g merges its prototype's entries, updates threshold
    if (tid < G) {
      const int g  = tid;
      const int cc = cand_cnt[g];
      const int ne = (cc > CAND_CAP) ? 32 : cc;
      for (int e = 0; e < ne; ++e) {
        float dv; int ix;
        if (cc > CAND_CAP) { dv = wv_dot[g][e >> 3][e & 7]; ix = wv_idx[g][e >> 3][e & 7]; }
        else               { dv = cand_dot[g][e];           ix = cand_idx[g][e]; }
        float mn = top_dot[g][0]; int ms = 0;
        #pragma unroll
        for (int k = 1; k < 8; ++k) { float t = top_dot[g][k]; if (t < mn) { mn = t; ms = k; } }
        if (dv > mn) { top_dot[g][ms] = dv; top_idx[g][ms] = ix; }
      }
      float mn = top_dot[g][0];
      #pragma unroll
      for (int k = 1; k < 8; ++k) mn = fminf(mn, top_dot[g][k]);
      thresh[g]   = mn;
      cand_cnt[g] = 0;
    }
    __syncthreads();
  }

  // write partial top-8 for (prototype, slice)
  if (tid < G) {
    const int g = tid;
    const int p = pg * G + g;
    #pragma unroll
    for (int k = 0; k < 8; ++k) {
      part_dot[(p * NS + ns) * 8 + k] = top_dot[g][k];
      part_idx[(p * NS + ns) * 8 + k] = top_idx[g][k];
    }
  }
}

// ---------------------------------------------------------------------------
// Kernel 2: per prototype, merge NS*8=64 partial entries -> exact top-8,
// gather + average the 8 neighbours, accumulate MSE into out[0].
// ---------------------------------------------------------------------------
__global__ __launch_bounds__(128) void merge_loss_kernel(
    const float* __restrict__ protos, const float* __restrict__ mem,
    const float* __restrict__ part_dot, const int* __restrict__ part_idx,
    float* __restrict__ out)
{
  const int p    = blockIdx.x;
  const int tid  = threadIdx.x;   // 128 threads = 2 waves
  const int lane = tid & 63;
  const int wid  = tid >> 6;

  __shared__ int   sel[8];
  __shared__ float wsum[2];

  if (wid == 0) {
    float v  = part_dot[p * 64 + lane];
    int   vi = part_idx[p * 64 + lane];
    #pragma unroll 1
    for (int k = 0; k < 8; ++k) {
      float m = v; int mi = vi;
      #pragma unroll
      for (int off = 32; off > 0; off >>= 1) {
        float om  = __shfl_xor(m, off);
        int   omi = __shfl_xor(mi, off);
        if (om > m || (om == m && omi < mi)) { m = om; mi = omi; }
      }
      if (lane == 0) sel[k] = mi;
      if (vi == mi) v = -FLT_MAX;
    }
  }
  __syncthreads();

  // tid = dimension index (0..127)
  float s = 0.f;
  #pragma unroll
  for (int z = 0; z < 8; ++z) s += mem[(size_t)sel[z] * D + tid];
  const float diff = s * 0.125f - protos[(size_t)p * D + tid];
  float sq = diff * diff;

  #pragma unroll
  for (int off = 32; off > 0; off >>= 1) sq += __shfl_down(sq, off);
  if (lane == 0) wsum[wid] = sq;
  __syncthreads();
  if (tid == 0) atomicAdd(out, (wsum[0] + wsum[1]) * (1.0f / ((float)P * (float)D)));
}

// ---------------------------------------------------------------------------
extern "C" void kernel_launch(void* const* d_in, const int* in_sizes, int n_in,
                              void* d_out, int out_size, void* d_ws, size_t ws_size,
                              hipStream_t stream) {
  const float* protos = (const float*)d_in[0];   // [2048, 128]
  const float* mem    = (const float*)d_in[1];   // [131072, 128]
  float* out = (float*)d_out;

  float* part_dot = (float*)d_ws;                                  // 512 KB
  int*   part_idx = (int*)((char*)d_ws + (size_t)P * NS * 8 * 4);  // 512 KB

  hipMemsetAsync(out, 0, out_size * sizeof(float), stream);
  topk_kernel<<<dim3((P / G) * NS), BT, 0, stream>>>(protos, mem, part_dot, part_idx);
  merge_loss_kernel<<<dim3(P), 128, 0, stream>>>(protos, mem, part_dot, part_idx, out);
}